// Round 9
// baseline (200.932 us; speedup 1.0000x reference)
//
#include <hip/hip_runtime.h>
#include <hip/hip_bf16.h>

#define B_SZ   4
#define DEC_SZ 128
#define ENC_SZ 512
#define H_SZ   768
#define OUT_N  (B_SZ * DEC_SZ * ENC_SZ)

typedef __attribute__((ext_vector_type(8))) short s8v;   // 8 bf16 (4 VGPRs)
typedef __attribute__((ext_vector_type(4))) float fvec4; // MFMA accumulator
typedef __attribute__((ext_vector_type(4))) float f4v;
typedef __attribute__((ext_vector_type(2))) float f2v;   // -> v_pk_* ops

// fp32 -> bf16, round-to-nearest-even
__device__ inline unsigned short f2bf(float x) {
  union { float f; unsigned u; } v; v.f = x;
  unsigned r = v.u + 0x7FFF + ((v.u >> 16) & 1);
  return (unsigned short)(r >> 16);
}

// load 8 k-contiguous fp32 -> bf16x8
__device__ inline s8v load8f(const float* p) {
  float4 a = ((const float4*)p)[0];
  float4 b = ((const float4*)p)[1];
  unsigned short r[8] = {f2bf(a.x), f2bf(a.y), f2bf(a.z), f2bf(a.w),
                         f2bf(b.x), f2bf(b.y), f2bf(b.z), f2bf(b.w)};
  return *(const s8v*)r;
}

// swizzle low-2-bits of an index: 0->0, 1->2, 2->1, 3->3 (self-inverse)
__device__ inline int swz2(int n) {
  return (n & ~3) | (((n & 1) << 1) | ((n >> 1) & 1));
}

// ---------------------------------------------------------------------------
// MFMA core: 128x64 tile, BK=32, 4 waves, wave w owns m rows [w*32, w*32+32).
// ---------------------------------------------------------------------------
__device__ inline void mfma_tile(unsigned short (*As)[40], unsigned short (*Bs)[40],
                                 int wm, int l16, int quad, fvec4 acc[2][4]) {
  s8v af[2], bf[4];
#pragma unroll
  for (int i = 0; i < 2; ++i) af[i] = *(const s8v*)&As[wm + i * 16 + l16][quad * 8];
#pragma unroll
  for (int j = 0; j < 4; ++j) bf[j] = *(const s8v*)&Bs[j * 16 + l16][quad * 8];
#pragma unroll
  for (int i = 0; i < 2; ++i)
#pragma unroll
    for (int j = 0; j < 4; ++j)
      acc[i][j] = __builtin_amdgcn_mfma_f32_16x16x32_bf16(af[i], bf[j], acc[i][j], 0, 0, 0);
}

// ---------------------------------------------------------------------------
// pe GEMM body: peT[h][(b,e)] = exp2(C2 * sum_k W1[k][h] * enc[(b,e)][k])
// W1 transposed during staging. Output tile layout (pair-swizzled for pk ops):
//   float4 idx ((b*8 + e/64)*192 + h/4)*64 + (e&63), components {h0,h2,h1,h3}.
// ---------------------------------------------------------------------------
__device__ inline void pe_body(const float* __restrict__ W1,
                               const float* __restrict__ enc,
                               float* __restrict__ peT, int bx, int by) {
  const int m0 = bx * 128;   // h
  const int n0 = by * 64;    // (b,e)

  __shared__ unsigned short As[128][40];
  __shared__ unsigned short Bs[64][40];

  const int tid  = threadIdx.x;
  const int wave = tid >> 6;
  const int lane = tid & 63;
  const int l16  = lane & 15;
  const int quad = lane >> 4;
  const int wm   = wave * 32;

  const int mloc = tid & 127, kh = tid >> 7;
  const float* aW = W1 + m0 + mloc;
  const int br = tid >> 2, bk = (tid & 3) * 8;
  const float* bE = enc + (size_t)(n0 + br) * H_SZ + bk;

  fvec4 acc[2][4];
#pragma unroll
  for (int i = 0; i < 2; ++i)
#pragma unroll
    for (int j = 0; j < 4; ++j) acc[i][j] = (fvec4)0.f;

  float pw[16];
  s8v pb;
#pragma unroll
  for (int j = 0; j < 16; ++j) pw[j] = aW[(size_t)(kh * 16 + j) * H_SZ];
  pb = load8f(bE);

  for (int k0 = 0; k0 < H_SZ; k0 += 32) {
    __syncthreads();
    {
      unsigned short s[16];
#pragma unroll
      for (int j = 0; j < 16; ++j) s[j] = f2bf(pw[j]);
      *(s8v*)&As[mloc][kh * 16]     = *(const s8v*)s;
      *(s8v*)&As[mloc][kh * 16 + 8] = *(const s8v*)(s + 8);
      *(s8v*)&Bs[br][bk] = pb;
    }
    __syncthreads();

    if (k0 + 32 < H_SZ) {
#pragma unroll
      for (int j = 0; j < 16; ++j) pw[j] = aW[(size_t)(k0 + 32 + kh * 16 + j) * H_SZ];
      pb = load8f(bE + k0 + 32);
    }
    mfma_tile(As, Bs, wm, l16, quad, acc);
  }

  const float C2 = 2.885390082f;  // 2 * log2(e)
#pragma unroll
  for (int i = 0; i < 2; ++i) {
    int mbase = m0 + wm + i * 16 + quad * 4;  // h; C/D row = quad*4+reg, col = l16
#pragma unroll
    for (int j = 0; j < 4; ++j) {
      int n = n0 + j * 16 + l16;
      // pair-swizzled component order {h0, h2, h1, h3}
      float4 o;
      o.x = __builtin_amdgcn_exp2f(acc[i][j][0] * C2);
      o.y = __builtin_amdgcn_exp2f(acc[i][j][2] * C2);
      o.z = __builtin_amdgcn_exp2f(acc[i][j][1] * C2);
      o.w = __builtin_amdgcn_exp2f(acc[i][j][3] * C2);
      int col = n >> 6, el = n & 63;   // col = b*8+es
      ((float4*)peT)[((size_t)col * 192 + (mbase >> 2)) * 64 + el] = o;
    }
  }
}

// ---------------------------------------------------------------------------
// pd GEMM body: pdm[(b,d)][swz2(h)] = exp2(C2 * sum_k dec[(b,d)][k] * W2[k][h])
// Columns stored pair-swizzled ({h0,h2,h1,h3} within each 4-group) to match pe.
// ---------------------------------------------------------------------------
__device__ inline void pd_body(const float* __restrict__ dec,
                               const float* __restrict__ W2,
                               float* __restrict__ pdm, int bx, int by) {
  const int m0 = bx * 128;   // (b,d)
  const int n0 = by * 64;    // h

  __shared__ unsigned short As[128][40];
  __shared__ unsigned short Bs[64][40];

  const int tid  = threadIdx.x;
  const int wave = tid >> 6;
  const int lane = tid & 63;
  const int l16  = lane & 15;
  const int quad = lane >> 4;
  const int wm   = wave * 32;

  int ar[2], ak[2];
#pragma unroll
  for (int i = 0; i < 2; ++i) {
    int seg = tid + 256 * i;
    ar[i] = seg >> 2; ak[i] = (seg & 3) * 8;
  }
  const int nloc = tid & 63, kq = tid >> 6;
  const float* bW = W2 + n0 + nloc;

  fvec4 acc[2][4];
#pragma unroll
  for (int i = 0; i < 2; ++i)
#pragma unroll
    for (int j = 0; j < 4; ++j) acc[i][j] = (fvec4)0.f;

  s8v pa[2];
  float qw[8];
#pragma unroll
  for (int i = 0; i < 2; ++i) pa[i] = load8f(dec + (size_t)(m0 + ar[i]) * H_SZ + ak[i]);
#pragma unroll
  for (int j = 0; j < 8; ++j) qw[j] = bW[(size_t)(kq * 8 + j) * H_SZ];

  for (int k0 = 0; k0 < H_SZ; k0 += 32) {
    __syncthreads();
    {
#pragma unroll
      for (int i = 0; i < 2; ++i) *(s8v*)&As[ar[i]][ak[i]] = pa[i];
      unsigned short s[8];
#pragma unroll
      for (int j = 0; j < 8; ++j) s[j] = f2bf(qw[j]);
      *(s8v*)&Bs[nloc][kq * 8] = *(const s8v*)s;
    }
    __syncthreads();

    if (k0 + 32 < H_SZ) {
#pragma unroll
      for (int i = 0; i < 2; ++i)
        pa[i] = load8f(dec + (size_t)(m0 + ar[i]) * H_SZ + k0 + 32 + ak[i]);
#pragma unroll
      for (int j = 0; j < 8; ++j) qw[j] = bW[(size_t)(k0 + 32 + kq * 8 + j) * H_SZ];
    }
    mfma_tile(As, Bs, wm, l16, quad, acc);
  }

  const float C2 = 2.885390082f;
#pragma unroll
  for (int i = 0; i < 2; ++i) {
    int mbase = m0 + wm + i * 16 + quad * 4;
#pragma unroll
    for (int j = 0; j < 4; ++j) {
      int ns = swz2(n0 + j * 16 + l16);   // pair-swizzled column
#pragma unroll
      for (int r = 0; r < 4; ++r)
        pdm[(size_t)(mbase + r) * H_SZ + ns] = __builtin_amdgcn_exp2f(acc[i][j][r] * C2);
    }
  }
}

// Both GEMMs in one launch; block 239 also writes pair-swizzled vtR.
__global__ __launch_bounds__(256) void gemm_both(const float* __restrict__ W1,
                                                 const float* __restrict__ enc,
                                                 const float* __restrict__ dec,
                                                 const float* __restrict__ W2,
                                                 const float* __restrict__ vt,
                                                 float* __restrict__ peT,
                                                 float* __restrict__ pdm,
                                                 float* __restrict__ vtR) {
  int bid = blockIdx.x;
  if (bid < 192) {
    pe_body(W1, enc, peT, bid % 6, bid / 6);
  } else {
    int r = bid - 192;
    if (bid == 239 && threadIdx.x < 192) {
      int p = threadIdx.x * 4;
#pragma unroll
      for (int j = 0; j < 4; ++j) vtR[p + j] = vt[swz2(p + j)];
    }
    pd_body(dec, W2, pdm, r % 4, r / 4);
  }
}

// ---------------------------------------------------------------------------
// Fused score + mask + outputs. Packed-FP32 quad-rcp batching:
// memory holds pair-swizzled quads {h0,h2,h1,h3}; per quad:
//   a2 = pk_fma(pe_lo, pd_lo, 1)    = {a0, a2}
//   b2 = pk_fma(pe_hi, pd_hi, 1)    = {a1, a3}
//   prod2 = a2*b2; num2 = pk_fma(v_lo, b2, v_hi*a2)
//   t += [num2.x*prod2.y + num2.y*prod2.x] * rcp(prod2.x*prod2.y)
// 5 pk + 4 scalar VALU + 1 rcp per 4 elements.
// Block = 512 thr (8 waves): wave = dw(4) x khalf(2); 96 quads/wave.
// Grid 1024 XCD-swizzled blocks -> 32 waves/CU.
// ---------------------------------------------------------------------------
__global__ __launch_bounds__(512) void score_out(const float* __restrict__ peT,
                                                 const float* __restrict__ pdm,
                                                 const float* __restrict__ vtR,
                                                 const float* __restrict__ mask,
                                                 float* __restrict__ out) {
  const int tid  = threadIdx.x;
  const int lane = tid & 63;
  const int wave = __builtin_amdgcn_readfirstlane(tid >> 6);
  const int dw   = wave & 3;
  const int kh   = wave >> 2;

  const int L    = blockIdx.x;
  const int xcd  = L & 7;
  const int slot = L >> 3;
  const int col  = xcd + 8 * (slot & 3);   // = b*8 + es
  const int b    = col >> 3;
  const int es   = col & 7;
  const int d    = (slot >> 2) * 4 + dw;

  // sumv = sum of all vt (order-independent; vtR is a permutation)
  float sumv = 0.f;
#pragma unroll
  for (int j = 0; j < 12; ++j) sumv += vtR[lane + 64 * j];
#pragma unroll
  for (int s = 1; s < 64; s <<= 1) sumv += __shfl_xor(sumv, s, 64);

  const float* pdrow = pdm + (size_t)(b * DEC_SZ + d) * H_SZ + kh * 384;  // uniform
  const float* vth   = vtR + kh * 384;
  const f4v* pe4 = (const f4v*)peT + ((size_t)col * 192 + kh * 96) * 64 + lane;

  float t0 = 0.f;
  const f2v one2 = {1.f, 1.f};
  f4v buf[8];
#pragma unroll
  for (int i = 0; i < 8; ++i) buf[i] = pe4[(size_t)i * 64];

#pragma unroll 8
  for (int c = 0; c < 96; ++c) {
    f4v cur = buf[c & 7];
    if (c + 8 < 96) buf[c & 7] = pe4[(size_t)(c + 8) * 64];
    f4v v4 = *(const f4v*)(vth + c * 4);     // uniform -> s_load
    f4v p4 = *(const f4v*)(pdrow + c * 4);   // uniform -> s_load
    f2v x  = __builtin_shufflevector(cur, cur, 0, 1);
    f2v y  = __builtin_shufflevector(cur, cur, 2, 3);
    f2v pa = __builtin_shufflevector(p4, p4, 0, 1);
    f2v pb = __builtin_shufflevector(p4, p4, 2, 3);
    f2v va = __builtin_shufflevector(v4, v4, 0, 1);
    f2v vb = __builtin_shufflevector(v4, v4, 2, 3);
    f2v a2 = __builtin_elementwise_fma(x, pa, one2);
    f2v b2 = __builtin_elementwise_fma(y, pb, one2);
    f2v prod2 = a2 * b2;
    f2v num2 = __builtin_elementwise_fma(va, b2, vb * a2);
    float num = fmaf(num2.y, prod2.x, num2.x * prod2.y);
    float den = prod2.x * prod2.y;
    t0 = fmaf(num, __builtin_amdgcn_rcpf(den), t0);
  }

  __shared__ float tred[4][64];
  if (kh) tred[dw][lane] = t0;
  __syncthreads();
  if (!kh) {
    float t = t0 + tred[dw][lane];
    const int e = es * 64 + lane;
    size_t idx = ((size_t)(b * DEC_SZ + d)) * ENC_SZ + e;
    float s = fmaf(-2.f, t, sumv);
    out[idx] = s + mask[idx];
    out[OUT_N + idx] = s;
  }
}

extern "C" void kernel_launch(void* const* d_in, const int* in_sizes, int n_in,
                              void* d_out, int out_size, void* d_ws, size_t ws_size,
                              hipStream_t stream) {
  (void)in_sizes; (void)n_in; (void)out_size; (void)ws_size;
  const float* dec  = (const float*)d_in[0];  // (B, DEC, H)
  const float* enc  = (const float*)d_in[1];  // (B, ENC, H)
  const float* mask = (const float*)d_in[2];  // (B, DEC, ENC)
  const float* W1   = (const float*)d_in[3];  // (H, H) (k, n)
  const float* W2   = (const float*)d_in[4];  // (H, H) (k, n)
  const float* vt   = (const float*)d_in[5];  // (H,)
  float* out = (float*)d_out;

  // Workspace layout
  float* peT = (float*)d_ws;                            // tiled (32,192,64,4) 6.29 MB
  float* pdm = peT + (size_t)H_SZ * B_SZ * ENC_SZ;      // (B*DEC, H) swizzled cols
  float* vtR = pdm + (size_t)B_SZ * DEC_SZ * H_SZ;      // 768 floats, pair-swizzled

  gemm_both<<<dim3(240), 256, 0, stream>>>(W1, enc, dec, W2, vt, peT, pdm, vtR);
  score_out<<<dim3(1024), 512, 0, stream>>>(peT, pdm, vtR, mask, out);
}

// Round 10
// 127.236 us; speedup vs baseline: 1.5792x; 1.5792x over previous
//
#include <hip/hip_runtime.h>
#include <hip/hip_bf16.h>

#define B_SZ   4
#define DEC_SZ 128
#define ENC_SZ 512
#define H_SZ   768
#define OUT_N  (B_SZ * DEC_SZ * ENC_SZ)

typedef __attribute__((ext_vector_type(8))) short s8v;   // 8 bf16 (4 VGPRs)
typedef __attribute__((ext_vector_type(4))) float fvec4; // MFMA accumulator

// fp32 -> bf16, round-to-nearest-even
__device__ inline unsigned short f2bf(float x) {
  union { float f; unsigned u; } v; v.f = x;
  unsigned r = v.u + 0x7FFF + ((v.u >> 16) & 1);
  return (unsigned short)(r >> 16);
}

// load 8 k-contiguous elements as bf16x8 (converting if fp32 source)
__device__ inline s8v load8(const unsigned short* p) { return *(const s8v*)p; }
__device__ inline s8v load8(const float* p) {
  float4 a = ((const float4*)p)[0];
  float4 b = ((const float4*)p)[1];
  unsigned short r[8] = {f2bf(a.x), f2bf(a.y), f2bf(a.z), f2bf(a.w),
                         f2bf(b.x), f2bf(b.y), f2bf(b.z), f2bf(b.w)};
  return *(const s8v*)r;
}

// ---------------------------------------------------------------------------
// Prep: transpose W (768x768 fp32, (k,n)) -> WT bf16 (n,k). z selects W1/W2.
// ---------------------------------------------------------------------------
__global__ __launch_bounds__(256) void transpose_w(const float* __restrict__ W1,
                                                   const float* __restrict__ W2,
                                                   unsigned short* __restrict__ T1,
                                                   unsigned short* __restrict__ T2) {
  const float* W = blockIdx.z ? W2 : W1;
  unsigned short* T = blockIdx.z ? T2 : T1;
  __shared__ float tile[64][65];
  int c0 = blockIdx.x * 64;
  int r0 = blockIdx.y * 64;
  int tx = threadIdx.x & 63, ty = threadIdx.x >> 6;
#pragma unroll
  for (int i = 0; i < 16; ++i) {
    int r = ty + i * 4;
    tile[r][tx] = W[(size_t)(r0 + r) * H_SZ + c0 + tx];
  }
  __syncthreads();
#pragma unroll
  for (int i = 0; i < 16; ++i) {
    int c = ty + i * 4;
    T[(size_t)(c0 + c) * H_SZ + r0 + tx] = f2bf(tile[tx][c]);
  }
}

// ---------------------------------------------------------------------------
// MFMA NT GEMM body + exp2 epilogue, register-prefetch double-buffered.
// E[m][n] = exp2(C2 * sum_k A[m][k]*B[n][k]); A,B k-contiguous rows (len H).
// Tile 128x64, BK=32, 4 waves; fp32 operands converted to bf16 during staging.
// TILED: m = h, n = (b*ENC+e); float4 store to pe tile layout
//        ((b*8 + e/64)*192 + h/4)*64 + (e&63), component h&3.
// ---------------------------------------------------------------------------
template <bool TILED, typename TA, typename TB>
__device__ inline void gemm_body(const TA* __restrict__ A, const TB* __restrict__ B,
                                 float* __restrict__ C, int ldc, int bx, int by) {
  const int m0 = bx * 128;
  const int n0 = by * 64;

  __shared__ unsigned short As[128][40];  // pad 40: 80 B rows
  __shared__ unsigned short Bs[64][40];

  const int tid  = threadIdx.x;
  const int wave = tid >> 6;
  const int lane = tid & 63;
  const int l16  = lane & 15;
  const int quad = lane >> 4;
  const int wm   = wave * 32;

  int ar[2], ak[2];
#pragma unroll
  for (int i = 0; i < 2; ++i) {
    int seg = tid + 256 * i;
    ar[i] = seg >> 2; ak[i] = (seg & 3) * 8;
  }
  const int br = tid >> 2, bk = (tid & 3) * 8;

  fvec4 acc[2][4];
#pragma unroll
  for (int i = 0; i < 2; ++i)
#pragma unroll
    for (int j = 0; j < 4; ++j) acc[i][j] = (fvec4)0.f;

  s8v pa[2], pb;
#pragma unroll
  for (int i = 0; i < 2; ++i) pa[i] = load8(A + (size_t)(m0 + ar[i]) * H_SZ + ak[i]);
  pb = load8(B + (size_t)(n0 + br) * H_SZ + bk);

  for (int k0 = 0; k0 < H_SZ; k0 += 32) {
    __syncthreads();
#pragma unroll
    for (int i = 0; i < 2; ++i) *(s8v*)&As[ar[i]][ak[i]] = pa[i];
    *(s8v*)&Bs[br][bk] = pb;
    __syncthreads();

    if (k0 + 32 < H_SZ) {
#pragma unroll
      for (int i = 0; i < 2; ++i)
        pa[i] = load8(A + (size_t)(m0 + ar[i]) * H_SZ + k0 + 32 + ak[i]);
      pb = load8(B + (size_t)(n0 + br) * H_SZ + k0 + 32 + bk);
    }

    s8v af[2], bf[4];
#pragma unroll
    for (int i = 0; i < 2; ++i) af[i] = *(const s8v*)&As[wm + i * 16 + l16][quad * 8];
#pragma unroll
    for (int j = 0; j < 4; ++j) bf[j] = *(const s8v*)&Bs[j * 16 + l16][quad * 8];
#pragma unroll
    for (int i = 0; i < 2; ++i)
#pragma unroll
      for (int j = 0; j < 4; ++j)
        acc[i][j] = __builtin_amdgcn_mfma_f32_16x16x32_bf16(af[i], bf[j], acc[i][j], 0, 0, 0);
  }

  const float C2 = 2.885390082f;  // 2 * log2(e)
#pragma unroll
  for (int i = 0; i < 2; ++i) {
    int mbase = m0 + wm + i * 16 + quad * 4;  // C/D: row = quad*4 + reg, col = l16
#pragma unroll
    for (int j = 0; j < 4; ++j) {
      int n = n0 + j * 16 + l16;
      if (TILED) {
        float4 o;
        o.x = __builtin_amdgcn_exp2f(acc[i][j][0] * C2);
        o.y = __builtin_amdgcn_exp2f(acc[i][j][1] * C2);
        o.z = __builtin_amdgcn_exp2f(acc[i][j][2] * C2);
        o.w = __builtin_amdgcn_exp2f(acc[i][j][3] * C2);
        int bIdx = n >> 9, es = (n >> 6) & 7, el = n & 63;
        ((float4*)C)[((size_t)(bIdx * 8 + es) * 192 + (mbase >> 2)) * 64 + el] = o;
      } else {
#pragma unroll
        for (int r = 0; r < 4; ++r)
          C[(size_t)(mbase + r) * ldc + n] = __builtin_amdgcn_exp2f(acc[i][j][r] * C2);
      }
    }
  }
}

// Both GEMMs in one launch: blocks 0..191 -> pe GEMM, 192..239 -> pd GEMM.
__global__ __launch_bounds__(256) void gemm_both(const unsigned short* __restrict__ W1T,
                                                 const float* __restrict__ enc,
                                                 const float* __restrict__ dec,
                                                 const unsigned short* __restrict__ W2T,
                                                 float* __restrict__ peT,
                                                 float* __restrict__ pdm) {
  int bid = blockIdx.x;
  if (bid < 192) {
    // peT tiled: m=h (768 -> 6 tiles), n=(b,e) (2048 -> 32 tiles)
    gemm_body<true>(W1T, enc, peT, 0, bid % 6, bid / 6);
  } else {
    // pdm[(b,d)][h]: m=(b,d) (512 -> 4 tiles), n=h (768 -> 12 tiles)
    int r = bid - 192;
    gemm_body<false>(dec, W2T, pdm, H_SZ, r % 4, r / 4);
  }
}

// ---------------------------------------------------------------------------
// Fused score + mask + outputs. Quad-rcp batching:
//   vk0/a+vk1/b+vk2/c+vk3/d = [(vk0*b+vk1*a)*cd + (vk2*d+vk3*c)*ab] / (ab*cd)
// with a_i = fma(pe_i, pd_i, 1): 14 VALU + 1 rcp per 4 k (vs 4 rcp @16cyc).
// Block = 512 thr (8 waves): wave = dw(4) x khalf(2); each wave does 96 quads;
// k-halves combined via 1KB LDS. Grid 1024 XCD-swizzled blocks -> 32 waves/CU.
// pe layout: float4[(b*8+es)*192 + k/4][64lane].
// ---------------------------------------------------------------------------
__global__ __launch_bounds__(512) void score_out(const float* __restrict__ peT,
                                                 const float* __restrict__ pdm,
                                                 const float* __restrict__ vt,
                                                 const float* __restrict__ mask,
                                                 float* __restrict__ out) {
  const int tid  = threadIdx.x;
  const int lane = tid & 63;
  const int wave = __builtin_amdgcn_readfirstlane(tid >> 6);
  const int dw   = wave & 3;     // which d of the block's 4
  const int kh   = wave >> 2;    // k half: 0 -> [0,384), 1 -> [384,768)

  const int L    = blockIdx.x;
  const int xcd  = L & 7;
  const int slot = L >> 3;
  const int col  = xcd + 8 * (slot & 3);   // = b*8 + es  (0..31)
  const int b    = col >> 3;
  const int es   = col & 7;
  const int d    = (slot >> 2) * 4 + dw;   // 0..127

  // sumv = sum over ALL 768 vt (identity uses full sum); cheap per wave
  float sumv = 0.f;
#pragma unroll
  for (int j = 0; j < 12; ++j) sumv += vt[lane + 64 * j];
#pragma unroll
  for (int s = 1; s < 64; s <<= 1) sumv += __shfl_xor(sumv, s, 64);

  const float* pdrow = pdm + (size_t)(b * DEC_SZ + d) * H_SZ + kh * 384;  // uniform
  const float* vth   = vt + kh * 384;
  const float4* pe4  = (const float4*)peT + ((size_t)col * 192 + kh * 96) * 64 + lane;

  float t0 = 0.f;
  float4 buf[8];
#pragma unroll
  for (int i = 0; i < 8; ++i) buf[i] = pe4[(size_t)i * 64];

#pragma unroll 8
  for (int c = 0; c < 96; ++c) {
    float4 cur = buf[c & 7];
    if (c + 8 < 96) buf[c & 7] = pe4[(size_t)(c + 8) * 64];
    float4 v4 = *(const float4*)(vth + c * 4);     // uniform -> s_load
    float4 p4 = *(const float4*)(pdrow + c * 4);   // uniform -> s_load
    float a  = fmaf(cur.x, p4.x, 1.f);
    float bq = fmaf(cur.y, p4.y, 1.f);
    float cq = fmaf(cur.z, p4.z, 1.f);
    float dq = fmaf(cur.w, p4.w, 1.f);
    float ab = a * bq, cd = cq * dq;
    float n01 = fmaf(v4.x, bq, v4.y * a);
    float n23 = fmaf(v4.z, dq, v4.w * cq);
    float num = fmaf(n23, ab, n01 * cd);
    float r = __builtin_amdgcn_rcpf(ab * cd);
    t0 = fmaf(num, r, t0);
  }

  __shared__ float tred[4][64];
  if (kh) tred[dw][lane] = t0;
  __syncthreads();
  if (!kh) {
    float t = t0 + tred[dw][lane];
    const int e = es * 64 + lane;
    size_t idx = ((size_t)(b * DEC_SZ + d)) * ENC_SZ + e;
    float s = fmaf(-2.f, t, sumv);
    out[idx] = s + mask[idx];
    out[OUT_N + idx] = s;
  }
}

extern "C" void kernel_launch(void* const* d_in, const int* in_sizes, int n_in,
                              void* d_out, int out_size, void* d_ws, size_t ws_size,
                              hipStream_t stream) {
  (void)in_sizes; (void)n_in; (void)out_size; (void)ws_size;
  const float* dec  = (const float*)d_in[0];  // (B, DEC, H)
  const float* enc  = (const float*)d_in[1];  // (B, ENC, H)
  const float* mask = (const float*)d_in[2];  // (B, DEC, ENC)
  const float* W1   = (const float*)d_in[3];  // (H, H) (k, n)
  const float* W2   = (const float*)d_in[4];  // (H, H) (k, n)
  const float* vt   = (const float*)d_in[5];  // (H,)
  float* out = (float*)d_out;

  // Workspace layout
  float* peT = (float*)d_ws;                            // tiled (B,8,192,64,4) 6.29 MB
  float* pdm = peT + (size_t)H_SZ * B_SZ * ENC_SZ;      // (B*DEC, H)   1.57 MB
  unsigned short* W1T = (unsigned short*)(pdm + (size_t)B_SZ * DEC_SZ * H_SZ);
  unsigned short* W2T = W1T + (size_t)H_SZ * H_SZ;

  transpose_w<<<dim3(12, 12, 2), 256, 0, stream>>>(W1, W2, W1T, W2T);
  gemm_both<<<dim3(240), 256, 0, stream>>>(W1T, enc, dec, W2T, peT, pdm);
  score_out<<<dim3(1024), 512, 0, stream>>>(peT, pdm, vt, mask, out);
}